// Round 7
// baseline (526.044 us; speedup 1.0000x reference)
//
#include <hip/hip_runtime.h>

typedef _Float16 half8 __attribute__((ext_vector_type(8)));
typedef float floatx4 __attribute__((ext_vector_type(4)));

#define LBF 2304   // Lb == Lf
#define K1  1152
#define LDK2 2304  // worst-case compacted stride (Kc can be up to 2304)

__device__ __forceinline__ void gll16(const _Float16* g, _Float16* l) {
    __builtin_amdgcn_global_load_lds((const __attribute__((address_space(1))) void*)g,
                                     (__attribute__((address_space(3))) void*)l, 16, 0, 0);
}

// decode Kc from signed pos'[2303] (excl-scan encoding: valid->e, masked->-e-1)
__device__ __forceinline__ int dec_kc(int s) { return (s >= 0) ? s + 1 : -s - 1; }

// 48x48 transpose permutation on [0,2304): involution P(P(x)) == x
__device__ __forceinline__ int permP(int x) { int a = x / 48; return (x - a * 48) * 48 + a; }

// ---------------- stage ds (blocks 0..9215) + mask scan (block 9216) ----------
__global__ void stage_scan(const float* __restrict__ f, const float* __restrict__ bsrc,
                           const float* __restrict__ mask,
                           float* __restrict__ ds, int* __restrict__ pos) {
    int tid = threadIdx.x;
    if (blockIdx.x < 9216) {
        long flat = (long)blockIdx.x * 256 + tid;   // [0, 2*4*128*2304)
        int p = flat % 2304;
        long rest = flat / 2304;
        int c = rest % 128;
        int b = (rest / 128) % 4;
        int t = rest / (128 * 4);
        int pi = p / 48, pj = p % 48;
        const float* src = t ? bsrc : f;
        ds[flat] = src[(((long)b * 128 + c) * 96 + 2 * pi) * 96 + 2 * pj];
        return;
    }
    // ---- scan block: mask -> signed compaction index pos' ----
    int mmb[9], loc[9]; int s = 0;
#pragma unroll
    for (int t = 0; t < 9; t++) {
        int p = tid * 9 + t;
        int pi = p / 48, pj = p % 48;
        float sm = 0.f;
#pragma unroll
        for (int u = 0; u < 3; u++)
#pragma unroll
            for (int v = 0; v < 3; v++) {
                int y = pi - 1 + u, x = pj - 1 + v;
                if ((unsigned)y < 48u && (unsigned)x < 48u)
                    sm += mask[(8 * y) * 384 + 8 * x];
            }
        int m = (sm == 0.f) ? 1 : 0;
        mmb[t] = m; loc[t] = s; s += m;
    }
    __shared__ int sh[256];
    sh[tid] = s; __syncthreads();
    for (int off = 1; off < 256; off <<= 1) {
        int v = (tid >= off) ? sh[tid - off] : 0;
        __syncthreads();
        sh[tid] += v;
        __syncthreads();
    }
    int excl = sh[tid] - s;
#pragma unroll
    for (int t = 0; t < 9; t++) {
        int e = excl + loc[t];
        pos[tid * 9 + t] = mmb[t] ? e : (-e - 1);
    }
}

// ---------------- prep: fp patches from ds (3x3, pad 1) ------------------------
__global__ void prep_fp(const float* __restrict__ ds, _Float16* __restrict__ fp) {
    int k = blockIdx.x * 128 + threadIdx.x;   // [0,1152)
    int p = blockIdx.y;                       // [0,2304)
    int b = blockIdx.z;
    int c = k / 9, r = k % 9, u = r / 3, v = r % 3;
    int pi = p / 48, pj = p % 48;
    int y = pi - 1 + u, x = pj - 1 + v;
    float val = 0.f;
    if ((unsigned)y < 48u && (unsigned)x < 48u)
        val = ds[((long)(b * 128 + c)) * 2304 + y * 48 + x];
    fp[((long)b * LBF + p) * K1 + k] = (_Float16)val;
}

// ---------------- prep: wn normalized background patches from ds ---------------
__global__ void prep_wn(const float* __restrict__ ds, _Float16* __restrict__ wn) {
    int p = blockIdx.x, b = blockIdx.y;
    int tid = threadIdx.x;  // 128 threads, 9 elems each
    int pi = p / 48, pj = p % 48;
    const float* dsb = ds + (long)(4 + b) * 128 * 2304;
    float w[9];
    float ss = 0.f;
#pragma unroll
    for (int t = 0; t < 9; t++) {
        int k = tid + t * 128;
        int c = k / 9, r = k % 9, u = r / 3, v = r % 3;
        int y = pi - 1 + u, x = pj - 1 + v;
        float val = 0.f;
        if ((unsigned)y < 48u && (unsigned)x < 48u)
            val = dsb[(long)c * 2304 + y * 48 + x];
        w[t] = val;
        ss += val * val;
    }
    for (int m = 32; m; m >>= 1) ss += __shfl_xor(ss, m);
    __shared__ float sh[2];
    if ((tid & 63) == 0) sh[tid >> 6] = ss;
    __syncthreads();
    float denom = sqrtf(sh[0] + sh[1] + 0.1152f);  // sum(w^2 + ESC)
    float inv = 1.f / denom;
#pragma unroll
    for (int t = 0; t < 9; t++) {
        int k = tid + t * 128;
        wn[((long)b * LBF + p) * K1 + k] = (_Float16)(w[t] * inv);
    }
}

// ---------------- prep: compacted Wt, line-efficient ---------------------------
__global__ void prep_wtc(const float* __restrict__ bsrc, const int* __restrict__ pos,
                         _Float16* __restrict__ wtc) {
    int p = blockIdx.x * 256 + threadIdx.x;   // [0,2304)
    int c = blockIdx.y;                       // [0,128)
    int b = blockIdx.z;
    int sp = pos[p];
    long base = ((long)b * 2048 + c * 16) * LDK2;
    if (sp < 0) {
        int kc = dec_kc(pos[2303]);
        int kp = (kc + 63) & ~63;
        int mo = p + sp + 1;                  // masked ordinal
        if (mo < kp - kc) {
#pragma unroll
            for (int n = 0; n < 16; n++)
                wtc[base + (long)n * LDK2 + kc + mo] = (_Float16)0.f;
        }
        return;
    }
    int pi = p / 48, pj = p % 48;
    const float* src = bsrc + ((long)b * 128 + c) * 96 * 96;
#pragma unroll
    for (int u = 0; u < 4; u++) {
        int y = 2 * pi - 1 + u;
        bool yok = (unsigned)y < 96u;
#pragma unroll
        for (int v = 0; v < 4; v++) {
            int x = 2 * pj - 1 + v;
            float val = 0.f;
            if (yok && (unsigned)x < 96u) val = src[y * 96 + x];
            wtc[base + (long)(u * 4 + v) * LDK2 + sp] = (_Float16)val;
        }
    }
}

// ======================= GEMM1: 128x128 tile, 4 waves, counted-vmcnt ==========
// 64 KB LDS -> 2 blocks/CU + T4 counted-vmcnt rolling pipeline + T1 XCD swizzle.
// R3 race fix: lgkmcnt(0) drained BEFORE the mid barrier (see R3 notes).
#define G1_REG 4096   // 128 * 32 halves (8 KB) per region

__global__ __launch_bounds__(256)
void gemm1_cv(const _Float16* __restrict__ A, const _Float16* __restrict__ B,
              float* __restrict__ C) {
    __shared__ _Float16 SA[4 * G1_REG];
    __shared__ _Float16 SB[4 * G1_REG];

    // 1296 blocks = 4 batch * 18 * 18; bijective XCD swizzle (1296 % 8 == 0)
    int bid = blockIdx.x;
    int wg = (bid & 7) * 162 + (bid >> 3);
    int z = wg / 324; int t = wg - z * 324;
    const int m0 = (t / 18) * 128, n0 = (t % 18) * 128;

    const _Float16* gA = A + (long)z * LBF * K1 + (long)m0 * K1;
    const _Float16* gB = B + (long)z * LBF * K1 + (long)n0 * K1;
    float* Cb = C + (long)z * LBF * LBF;

    const int tid = threadIdx.x;
    const int wave = tid >> 6, lane = tid & 63;
    const int lm = lane & 15, q = lane >> 4;
    const int wm = wave >> 1, wn_ = wave & 1;
    const int soff = (q ^ ((lm >> 1) & 3)) * 8;
    const int srow = lane >> 2;                               // row in 16-row chunk
    const int scol = ((lane & 3) ^ ((lane >> 3) & 3)) * 8;    // swizzled k-halves

    floatx4 acc[4][4] = {};

    auto stA = [&](int reg, int kcol) {  // 8 KB region: 2 glls/thread
        _Float16* dst = SA + reg * G1_REG + wave * 1024;
        gll16(gA + (long)(wave * 32 + srow) * K1 + kcol + scol, dst);
        gll16(gA + (long)(wave * 32 + 16 + srow) * K1 + kcol + scol, dst + 512);
    };
    auto stB = [&](int reg, int kcol) {
        _Float16* dst = SB + reg * G1_REG + wave * 1024;
        gll16(gB + (long)(wave * 32 + srow) * K1 + kcol + scol, dst);
        gll16(gB + (long)(wave * 32 + 16 + srow) * K1 + kcol + scol, dst + 512);
    };
    auto ldA = [&](int reg, int i) -> half8 {
        return *(const half8*)&SA[reg * G1_REG + (wm * 64 + i * 16 + lm) * 32 + soff];
    };
    auto ldB = [&](int reg, int j) -> half8 {
        return *(const half8*)&SB[reg * G1_REG + (wn_ * 64 + j * 16 + lm) * 32 + soff];
    };

    // prologue: [0][0]<-t0ks0, [0][1]<-t0ks1, [1][0]<-t1ks0  (12 glls/thread)
    stA(0, 0);  stB(0, 0);
    stA(1, 32); stB(1, 32);
    stA(2, 64); stB(2, 64);
    asm volatile("s_waitcnt vmcnt(8)" ::: "memory");  // oldest batch (t0ks0) landed
    __builtin_amdgcn_s_barrier();

    for (int k = 0; k < 18; ++k) {
        const int b = k & 1;
        const int rg0 = b * 2, rg1 = rg0 + 1, og1 = (b ^ 1) * 2 + 1;
        // ---------- phase q0: compute ks0 ----------
        {
            half8 af[4], bf[4];
#pragma unroll
            for (int i = 0; i < 4; ++i) af[i] = ldA(rg0, i);
#pragma unroll
            for (int j = 0; j < 4; ++j) bf[j] = ldB(rg0, j);
            if (k + 1 < 18) {
                int kc = (k + 1) * 64 + 32;
                stA(og1, kc); stB(og1, kc);
                asm volatile("s_waitcnt vmcnt(8) lgkmcnt(0)" ::: "memory");
            } else {
                asm volatile("s_waitcnt vmcnt(0) lgkmcnt(0)" ::: "memory");
            }
            __builtin_amdgcn_s_barrier();
            __builtin_amdgcn_sched_barrier(0);
            __builtin_amdgcn_s_setprio(1);
#pragma unroll
            for (int i = 0; i < 4; ++i)
#pragma unroll
                for (int j = 0; j < 4; ++j)
                    acc[i][j] = __builtin_amdgcn_mfma_f32_16x16x32_f16(af[i], bf[j], acc[i][j], 0, 0, 0);
            __builtin_amdgcn_s_setprio(0);
            __builtin_amdgcn_sched_barrier(0);
            __builtin_amdgcn_s_barrier();
        }
        // ---------- phase q1: compute ks1 ----------
        {
            half8 af[4], bf[4];
#pragma unroll
            for (int i = 0; i < 4; ++i) af[i] = ldA(rg1, i);
#pragma unroll
            for (int j = 0; j < 4; ++j) bf[j] = ldB(rg1, j);
            if (k + 2 < 18) {
                int kc = (k + 2) * 64;
                stA(rg0, kc); stB(rg0, kc);
                asm volatile("s_waitcnt vmcnt(8) lgkmcnt(0)" ::: "memory");
            } else {
                asm volatile("s_waitcnt vmcnt(0) lgkmcnt(0)" ::: "memory");
            }
            __builtin_amdgcn_s_barrier();
            __builtin_amdgcn_sched_barrier(0);
            __builtin_amdgcn_s_setprio(1);
#pragma unroll
            for (int i = 0; i < 4; ++i)
#pragma unroll
                for (int j = 0; j < 4; ++j)
                    acc[i][j] = __builtin_amdgcn_mfma_f32_16x16x32_f16(af[i], bf[j], acc[i][j], 0, 0, 0);
            __builtin_amdgcn_s_setprio(0);
            __builtin_amdgcn_sched_barrier(0);
            __builtin_amdgcn_s_barrier();
        }
    }

    // C/D layout: col = lane&15, row = (lane>>4)*4 + reg   [m89-verified]
    const int col = n0 + wn_ * 64 + lm;
#pragma unroll
    for (int i = 0; i < 4; ++i) {
        const int row = m0 + wm * 64 + i * 16 + q * 4;
#pragma unroll
        for (int j = 0; j < 4; ++j)
#pragma unroll
            for (int r = 0; r < 4; ++r)
                Cb[(long)(row + r) * LBF + col + j * 16] = acc[i][j][r];
    }
}

// ---------------- NT GEMM, BK=64, double-buffered LDS (R6 winner) — GEMM2 -----
__device__ __forceinline__ void gemm_compute(const _Float16* lA, const _Float16* lB,
                                             floatx4 (&acc)[4][4],
                                             int wr, int wc, int lm, int pcp) {
    half8 af[4], bf[4];
#pragma unroll
    for (int t = 0; t < 4; t++) {
        af[t] = *(const half8*)&lA[(wr * 64 + t * 16 + lm) * 64 + pcp];
        bf[t] = *(const half8*)&lB[(wc * 64 + t * 16 + lm) * 64 + pcp];
    }
#pragma unroll
    for (int i = 0; i < 4; i++)
#pragma unroll
        for (int j = 0; j < 4; j++)
            acc[i][j] = __builtin_amdgcn_mfma_f32_16x16x32_f16(af[i], bf[j], acc[i][j], 0, 0, 0);
#pragma unroll
    for (int t = 0; t < 4; t++) {
        af[t] = *(const half8*)&lA[(wr * 64 + t * 16 + lm) * 64 + (pcp ^ 32)];
        bf[t] = *(const half8*)&lB[(wc * 64 + t * 16 + lm) * 64 + (pcp ^ 32)];
    }
#pragma unroll
    for (int i = 0; i < 4; i++)
#pragma unroll
        for (int j = 0; j < 4; j++)
            acc[i][j] = __builtin_amdgcn_mfma_f32_16x16x32_f16(af[i], bf[j], acc[i][j], 0, 0, 0);
}

__global__ __launch_bounds__(256)
void gemm_nt64(const _Float16* __restrict__ A, const _Float16* __restrict__ B,
               float* __restrict__ C, int M, int N, int ldk, int swapxy,
               const int* __restrict__ Kpos, int Kstat, long sA, long sB, long sC) {
    A += blockIdx.z * sA; B += blockIdx.z * sB; C += blockIdx.z * sC;
    int K;
    if (Kpos) { int kc = dec_kc(Kpos[0]); K = (kc + 63) & ~63; }
    else K = Kstat;
    const int tid = threadIdx.x;
    const int lane = tid & 63, wave = tid >> 6;
    const int wr = wave >> 1, wc = wave & 1;
    const int bm = swapxy ? blockIdx.x : blockIdx.y;
    const int bn = swapxy ? blockIdx.y : blockIdx.x;
    const int m0 = bm * 128, n0 = bn * 128;

    __shared__ _Float16 sm[4][128 * 64];   // [buf*2 + (A=0/B=1)]: 4 x 16 KB

    floatx4 acc[4][4] = {};

    const int lm = lane & 15, q = lane >> 4;
    const int pcp = (q ^ (lm & 7)) * 8;      // substep-0 phys offset (halves)

    const int srow8 = lane >> 3;
    const int gc = ((lane & 7) ^ srow8) * 8;  // global halves offset (XOR swizzle)
    const _Float16* gA[4]; const _Float16* gB[4];
    int dOff[4];
#pragma unroll
    for (int c = 0; c < 4; c++) {
        int r = (wave * 4 + c) * 8 + srow8;
        gA[c] = A + (long)(m0 + r) * ldk + gc;
        gB[c] = B + (long)(n0 + r) * ldk + gc;
        dOff[c] = (wave * 4 + c) * 512;
    }

    if (K > 0) {
#pragma unroll
        for (int c = 0; c < 4; c++) gll16(gA[c], &sm[0][dOff[c]]);
#pragma unroll
        for (int c = 0; c < 4; c++) gll16(gB[c], &sm[1][dOff[c]]);
        __syncthreads();
        int k0 = 0, buf = 0;
        while (true) {
            int kn = k0 + 64;
            if (kn < K) {
                const int nb = (buf ^ 1) * 2;
#pragma unroll
                for (int c = 0; c < 4; c++) gll16(gA[c] + kn, &sm[nb][dOff[c]]);
#pragma unroll
                for (int c = 0; c < 4; c++) gll16(gB[c] + kn, &sm[nb + 1][dOff[c]]);
            }
            gemm_compute(sm[buf * 2], sm[buf * 2 + 1], acc, wr, wc, lm, pcp);
            __syncthreads();
            k0 = kn; buf ^= 1;
            if (k0 >= K) break;
        }
    }

    // C/D layout: col = lane&15, row = (lane>>4)*4 + reg   [m89-verified]
    const int col = n0 + wc * 64 + lm;
    const int rowq = q * 4;
#pragma unroll
    for (int i = 0; i < 4; i++) {
        int row = m0 + wr * 64 + i * 16 + rowq;
#pragma unroll
        for (int j = 0; j < 4; j++)
#pragma unroll
            for (int r = 0; r < 4; r++)
                C[(long)(row + r) * N + col + j * 16] = acc[i][j][r];
    }
}

// ---------------- fuse pass 1: G[y][w] = sum_e ST[P(y)+e][P(w)+e] (bounded) ---
// One block per G row y. Reads 3 coalesced ST rows into LDS; e-stencil read at
// lane-consecutive LDS columns (conflict-free); permuted per-element stores fill
// the full G row (L2 write-combines to full lines). Exactness vs the verified
// fuse_sm: taps (P(y)+e, P(w)+e) bounded to [0,LBF) — identical index algebra.
__global__ __launch_bounds__(256)
void fuse1p(const float* __restrict__ STp, float* __restrict__ G) {
    int y = blockIdx.x;
    int slot = blockIdx.y;                 // batch pair slot
    const float* S = STp + (long)slot * LBF * LBF;
    float* Grow = G + (long)slot * LBF * LBF + (long)y * LBF;

    int r = permP(y);
    __shared__ float L[3][LBF];
    int tid = threadIdx.x;
    // load rows r-1, r, r+1 (skip OOB; predicated taps never read those slots)
#pragma unroll
    for (int s = 0; s < 3; s++) {
        int rr = r - 1 + s;
        if ((unsigned)rr < (unsigned)LBF) {
            const float4* src = (const float4*)(S + (long)rr * LBF);
            float4* dst = (float4*)L[s];
            for (int i = tid; i < LBF / 4; i += 256) dst[i] = src[i];
        }
    }
    __syncthreads();

    bool rok0 = (r > 0), rok2 = (r < LBF - 1);
#pragma unroll
    for (int u = 0; u < 9; u++) {
        int m = tid + u * 256;
        float acc = L[1][m];
        if (rok0 && m > 0)       acc += L[0][m - 1];
        if (rok2 && m < LBF - 1) acc += L[2][m + 1];
        Grow[permP(m)] = acc;
    }
}

// ---------------- fuse pass 2: 3-row diag stencil on G + softmax + compaction -
// Block y0 -> output row j = P(y0). v[w] = sum_d2 bounded G[y0+d2][w+d2];
// i = P(w), masked positions contribute exp(0-mx) to the denominator (matches
// reference att*mm semantics), write orow[pos[i]], zero-pad tail to 64-align.
__global__ __launch_bounds__(256)
void fuse2sm(const float* __restrict__ G, const int* __restrict__ pos,
             _Float16* __restrict__ attTcp) {
    int y0 = blockIdx.x;
    int slot = blockIdx.y;
    int tid = threadIdx.x;
    const float* Gb = G + (long)slot * LBF * LBF;
    int j = permP(y0);
    _Float16* orow = attTcp + ((long)slot * LBF + j) * LDK2;

    const float* g0 = Gb + (long)(y0 - 1) * LBF;
    const float* g1 = Gb + (long)y0 * LBF;
    const float* g2 = Gb + (long)(y0 + 1) * LBF;
    bool yok0 = (y0 > 0), yok2 = (y0 < LBF - 1);

    float v[9]; int ps[9];
    float mx = -1e30f;
#pragma unroll
    for (int u = 0; u < 9; u++) {
        int w = tid + u * 256;
        float a = g1[w];
        if (yok0 && w > 0)       a += g0[w - 1];
        if (yok2 && w < LBF - 1) a += g2[w + 1];
        int i = permP(w);
        int sp = pos[i];
        ps[u] = sp;
        float xv = (sp >= 0) ? a * 10.f : 0.f;
        v[u] = xv;
        mx = fmaxf(mx, xv);
    }
    for (int m = 32; m; m >>= 1) mx = fmaxf(mx, __shfl_xor(mx, m));
    __shared__ float sh[4], sh2[4];
    if ((tid & 63) == 0) sh[tid >> 6] = mx;
    __syncthreads();
    mx = fmaxf(fmaxf(sh[0], sh[1]), fmaxf(sh[2], sh[3]));
    float sum = 0.f;
#pragma unroll
    for (int u = 0; u < 9; u++) { v[u] = __expf(v[u] - mx); sum += v[u]; }
    for (int m = 32; m; m >>= 1) sum += __shfl_xor(sum, m);
    if ((tid & 63) == 0) sh2[tid >> 6] = sum;
    __syncthreads();
    sum = sh2[0] + sh2[1] + sh2[2] + sh2[3];
    float inv = 1.f / sum;
#pragma unroll
    for (int u = 0; u < 9; u++) {
        if (ps[u] >= 0) orow[ps[u]] = (_Float16)(v[u] * inv);
    }
    int kc = dec_kc(pos[2303]);
    int kp = (kc + 63) & ~63;
    if (tid < kp - kc) orow[kc + tid] = (_Float16)0.f;
}

// ---------------- scatter from MT[n][p]: coalesced transposed-conv gather -----
__global__ void scatter_out(const float* __restrict__ MT_, float* __restrict__ out) {
    int yx = blockIdx.x * 256 + threadIdx.x;  // [0, 9216)
    int c = blockIdx.y, b = blockIdx.z;
    int y = yx / 96, x = yx % 96;
    const float* Mb = MT_ + (long)b * 2048 * LBF;
    float s = 0.f;
    for (int uu = (y + 1) & 1; uu < 4; uu += 2) {
        int fi = (y + 1 - uu) >> 1;
        if ((unsigned)fi >= 48u) continue;
        for (int vv = (x + 1) & 1; vv < 4; vv += 2) {
            int fj = (x + 1 - vv) >> 1;
            if ((unsigned)fj >= 48u) continue;
            s += Mb[(long)(c * 16 + uu * 4 + vv) * LBF + fi * 48 + fj];
        }
    }
    out[(((long)b * 128 + c) * 96 + y) * 96 + x] = 0.25f * s;
}

extern "C" void kernel_launch(void* const* d_in, const int* in_sizes, int n_in,
                              void* d_out, int out_size, void* d_ws, size_t ws_size,
                              hipStream_t stream) {
    const float* f    = (const float*)d_in[0];
    const float* bsrc = (const float*)d_in[1];
    const float* mask = (const float*)d_in[2];
    float* out = (float*)d_out;

    char* ws = (char*)d_ws;
    const size_t offR1  = 84934656;
    const size_t offWn  = offR1 + 21233664;
    const size_t offWtc = offR1 + 42467328;
    const size_t offFT1 = offWtc + 37748736;          // 165150720
    const size_t offPos = offFT1 + 2ul * 21233664;    // 207618048
    const size_t NEED   = offPos + 9216;              // 207627264
    if (ws_size < NEED) return;  // visible failure, no OOB writes

    float*    ST    = (float*)(ws + 0);
    float*    MT    = (float*)(ws + 0);
    _Float16* fp    = (_Float16*)(ws + offR1);
    _Float16* wn    = (_Float16*)(ws + offWn);
    _Float16* attTc = (_Float16*)(ws + offR1);
    _Float16* Wtc   = (_Float16*)(ws + offWtc);
    float*    ds    = (float*)(ws + offFT1);
    float*    Gbuf  = (float*)(ws + offFT1);   // 2 x 21.2 MB slots (ds is dead)
    int*      pos   = (int*)(ws + offPos);

    stage_scan<<<dim3(9217), 256, 0, stream>>>(f, bsrc, mask, ds, pos);
    prep_fp<<<dim3(9, 2304, 4), 128, 0, stream>>>(ds, fp);
    prep_wn<<<dim3(2304, 4), 128, 0, stream>>>(ds, wn);
    prep_wtc<<<dim3(9, 128, 4), 256, 0, stream>>>(bsrc, pos, Wtc);

    // GEMM1: ST[j,i] = sum_k fp[j,k] * wn[i,k]  (static K=1152)
    gemm1_cv<<<dim3(1296), 256, 0, stream>>>(fp, wn, ST);

    // fused double-diagonal + softmax, two batches per pass (G fits dead ds slot)
    for (int bb0 = 0; bb0 < 4; bb0 += 2) {
        fuse1p<<<dim3(LBF, 2), 256, 0, stream>>>(ST + (long)bb0 * LBF * LBF, Gbuf);
        fuse2sm<<<dim3(LBF, 2), 256, 0, stream>>>(Gbuf, pos,
            attTc + (long)bb0 * LBF * LDK2);
    }

    // GEMM2 transposed output, R4 block-order: x sweeps Wtc (A), y pins attTc (B)
    gemm_nt64<<<dim3(16, 18, 4), 256, 0, stream>>>(Wtc, attTc, MT, 2048, 2304, LDK2, 1,
        pos + 2303, 0, (long)2048 * LDK2, (long)2304 * LDK2, (long)2048 * 2304);

    scatter_out<<<dim3(36, 128, 4), 256, 0, stream>>>(MT, out);
}

// Round 8
// 461.963 us; speedup vs baseline: 1.1387x; 1.1387x over previous
//
#include <hip/hip_runtime.h>

typedef _Float16 half8 __attribute__((ext_vector_type(8)));
typedef float floatx4 __attribute__((ext_vector_type(4)));

#define LBF 2304   // Lb == Lf
#define K1  1152
#define LDK2 2304  // worst-case compacted stride (Kc can be up to 2304)

__device__ __forceinline__ void gll16(const _Float16* g, _Float16* l) {
    __builtin_amdgcn_global_load_lds((const __attribute__((address_space(1))) void*)g,
                                     (__attribute__((address_space(3))) void*)l, 16, 0, 0);
}

// decode Kc from signed pos'[2303] (excl-scan encoding: valid->e, masked->-e-1)
__device__ __forceinline__ int dec_kc(int s) { return (s >= 0) ? s + 1 : -s - 1; }

// ---------------- stage ds (blocks 0..9215) + mask scan (block 9216) ----------
__global__ void stage_scan(const float* __restrict__ f, const float* __restrict__ bsrc,
                           const float* __restrict__ mask,
                           float* __restrict__ ds, int* __restrict__ pos) {
    int tid = threadIdx.x;
    if (blockIdx.x < 9216) {
        long flat = (long)blockIdx.x * 256 + tid;   // [0, 2*4*128*2304)
        int p = flat % 2304;
        long rest = flat / 2304;
        int c = rest % 128;
        int b = (rest / 128) % 4;
        int t = rest / (128 * 4);
        int pi = p / 48, pj = p % 48;
        const float* src = t ? bsrc : f;
        ds[flat] = src[(((long)b * 128 + c) * 96 + 2 * pi) * 96 + 2 * pj];
        return;
    }
    // ---- scan block: mask -> signed compaction index pos' ----
    int mmb[9], loc[9]; int s = 0;
#pragma unroll
    for (int t = 0; t < 9; t++) {
        int p = tid * 9 + t;
        int pi = p / 48, pj = p % 48;
        float sm = 0.f;
#pragma unroll
        for (int u = 0; u < 3; u++)
#pragma unroll
            for (int v = 0; v < 3; v++) {
                int y = pi - 1 + u, x = pj - 1 + v;
                if ((unsigned)y < 48u && (unsigned)x < 48u)
                    sm += mask[(8 * y) * 384 + 8 * x];
            }
        int m = (sm == 0.f) ? 1 : 0;
        mmb[t] = m; loc[t] = s; s += m;
    }
    __shared__ int sh[256];
    sh[tid] = s; __syncthreads();
    for (int off = 1; off < 256; off <<= 1) {
        int v = (tid >= off) ? sh[tid - off] : 0;
        __syncthreads();
        sh[tid] += v;
        __syncthreads();
    }
    int excl = sh[tid] - s;
#pragma unroll
    for (int t = 0; t < 9; t++) {
        int e = excl + loc[t];
        pos[tid * 9 + t] = mmb[t] ? e : (-e - 1);
    }
}

// ---------------- prep: fp patches from ds (3x3, pad 1) ------------------------
__global__ void prep_fp(const float* __restrict__ ds, _Float16* __restrict__ fp) {
    int k = blockIdx.x * 128 + threadIdx.x;   // [0,1152)
    int p = blockIdx.y;                       // [0,2304)
    int b = blockIdx.z;
    int c = k / 9, r = k % 9, u = r / 3, v = r % 3;
    int pi = p / 48, pj = p % 48;
    int y = pi - 1 + u, x = pj - 1 + v;
    float val = 0.f;
    if ((unsigned)y < 48u && (unsigned)x < 48u)
        val = ds[((long)(b * 128 + c)) * 2304 + y * 48 + x];
    fp[((long)b * LBF + p) * K1 + k] = (_Float16)val;
}

// ---------------- prep: wn normalized background patches from ds ---------------
__global__ void prep_wn(const float* __restrict__ ds, _Float16* __restrict__ wn) {
    int p = blockIdx.x, b = blockIdx.y;
    int tid = threadIdx.x;  // 128 threads, 9 elems each
    int pi = p / 48, pj = p % 48;
    const float* dsb = ds + (long)(4 + b) * 128 * 2304;
    float w[9];
    float ss = 0.f;
#pragma unroll
    for (int t = 0; t < 9; t++) {
        int k = tid + t * 128;
        int c = k / 9, r = k % 9, u = r / 3, v = r % 3;
        int y = pi - 1 + u, x = pj - 1 + v;
        float val = 0.f;
        if ((unsigned)y < 48u && (unsigned)x < 48u)
            val = dsb[(long)c * 2304 + y * 48 + x];
        w[t] = val;
        ss += val * val;
    }
    for (int m = 32; m; m >>= 1) ss += __shfl_xor(ss, m);
    __shared__ float sh[2];
    if ((tid & 63) == 0) sh[tid >> 6] = ss;
    __syncthreads();
    float denom = sqrtf(sh[0] + sh[1] + 0.1152f);  // sum(w^2 + ESC)
    float inv = 1.f / denom;
#pragma unroll
    for (int t = 0; t < 9; t++) {
        int k = tid + t * 128;
        wn[((long)b * LBF + p) * K1 + k] = (_Float16)(w[t] * inv);
    }
}

// ---------------- prep: compacted Wt, line-efficient ---------------------------
__global__ void prep_wtc(const float* __restrict__ bsrc, const int* __restrict__ pos,
                         _Float16* __restrict__ wtc) {
    int p = blockIdx.x * 256 + threadIdx.x;   // [0,2304)
    int c = blockIdx.y;                       // [0,128)
    int b = blockIdx.z;
    int sp = pos[p];
    long base = ((long)b * 2048 + c * 16) * LDK2;
    if (sp < 0) {
        int kc = dec_kc(pos[2303]);
        int kp = (kc + 63) & ~63;
        int mo = p + sp + 1;                  // masked ordinal
        if (mo < kp - kc) {
#pragma unroll
            for (int n = 0; n < 16; n++)
                wtc[base + (long)n * LDK2 + kc + mo] = (_Float16)0.f;
        }
        return;
    }
    int pi = p / 48, pj = p % 48;
    const float* src = bsrc + ((long)b * 128 + c) * 96 * 96;
#pragma unroll
    for (int u = 0; u < 4; u++) {
        int y = 2 * pi - 1 + u;
        bool yok = (unsigned)y < 96u;
#pragma unroll
        for (int v = 0; v < 4; v++) {
            int x = 2 * pj - 1 + v;
            float val = 0.f;
            if (yok && (unsigned)x < 96u) val = src[y * 96 + x];
            wtc[base + (long)(u * 4 + v) * LDK2 + sp] = (_Float16)val;
        }
    }
}

// ======================= GEMM1: 128x128 tile, 4 waves, counted-vmcnt ==========
// 64 KB LDS -> 2 blocks/CU + T4 counted-vmcnt rolling pipeline + T1 XCD swizzle.
// R3 race fix: lgkmcnt(0) drained BEFORE the mid barrier (see R3 notes).
#define G1_REG 4096   // 128 * 32 halves (8 KB) per region

__global__ __launch_bounds__(256)
void gemm1_cv(const _Float16* __restrict__ A, const _Float16* __restrict__ B,
              float* __restrict__ C) {
    __shared__ _Float16 SA[4 * G1_REG];
    __shared__ _Float16 SB[4 * G1_REG];

    // 1296 blocks = 4 batch * 18 * 18; bijective XCD swizzle (1296 % 8 == 0)
    int bid = blockIdx.x;
    int wg = (bid & 7) * 162 + (bid >> 3);
    int z = wg / 324; int t = wg - z * 324;
    const int m0 = (t / 18) * 128, n0 = (t % 18) * 128;

    const _Float16* gA = A + (long)z * LBF * K1 + (long)m0 * K1;
    const _Float16* gB = B + (long)z * LBF * K1 + (long)n0 * K1;
    float* Cb = C + (long)z * LBF * LBF;

    const int tid = threadIdx.x;
    const int wave = tid >> 6, lane = tid & 63;
    const int lm = lane & 15, q = lane >> 4;
    const int wm = wave >> 1, wn_ = wave & 1;
    const int soff = (q ^ ((lm >> 1) & 3)) * 8;
    const int srow = lane >> 2;                               // row in 16-row chunk
    const int scol = ((lane & 3) ^ ((lane >> 3) & 3)) * 8;    // swizzled k-halves

    floatx4 acc[4][4] = {};

    auto stA = [&](int reg, int kcol) {  // 8 KB region: 2 glls/thread
        _Float16* dst = SA + reg * G1_REG + wave * 1024;
        gll16(gA + (long)(wave * 32 + srow) * K1 + kcol + scol, dst);
        gll16(gA + (long)(wave * 32 + 16 + srow) * K1 + kcol + scol, dst + 512);
    };
    auto stB = [&](int reg, int kcol) {
        _Float16* dst = SB + reg * G1_REG + wave * 1024;
        gll16(gB + (long)(wave * 32 + srow) * K1 + kcol + scol, dst);
        gll16(gB + (long)(wave * 32 + 16 + srow) * K1 + kcol + scol, dst + 512);
    };
    auto ldA = [&](int reg, int i) -> half8 {
        return *(const half8*)&SA[reg * G1_REG + (wm * 64 + i * 16 + lm) * 32 + soff];
    };
    auto ldB = [&](int reg, int j) -> half8 {
        return *(const half8*)&SB[reg * G1_REG + (wn_ * 64 + j * 16 + lm) * 32 + soff];
    };

    // prologue: [0][0]<-t0ks0, [0][1]<-t0ks1, [1][0]<-t1ks0  (12 glls/thread)
    stA(0, 0);  stB(0, 0);
    stA(1, 32); stB(1, 32);
    stA(2, 64); stB(2, 64);
    asm volatile("s_waitcnt vmcnt(8)" ::: "memory");  // oldest batch (t0ks0) landed
    __builtin_amdgcn_s_barrier();

    for (int k = 0; k < 18; ++k) {
        const int b = k & 1;
        const int rg0 = b * 2, rg1 = rg0 + 1, og1 = (b ^ 1) * 2 + 1;
        // ---------- phase q0: compute ks0 ----------
        {
            half8 af[4], bf[4];
#pragma unroll
            for (int i = 0; i < 4; ++i) af[i] = ldA(rg0, i);
#pragma unroll
            for (int j = 0; j < 4; ++j) bf[j] = ldB(rg0, j);
            if (k + 1 < 18) {
                int kc = (k + 1) * 64 + 32;
                stA(og1, kc); stB(og1, kc);
                asm volatile("s_waitcnt vmcnt(8) lgkmcnt(0)" ::: "memory");
            } else {
                asm volatile("s_waitcnt vmcnt(0) lgkmcnt(0)" ::: "memory");
            }
            __builtin_amdgcn_s_barrier();
            __builtin_amdgcn_sched_barrier(0);
            __builtin_amdgcn_s_setprio(1);
#pragma unroll
            for (int i = 0; i < 4; ++i)
#pragma unroll
                for (int j = 0; j < 4; ++j)
                    acc[i][j] = __builtin_amdgcn_mfma_f32_16x16x32_f16(af[i], bf[j], acc[i][j], 0, 0, 0);
            __builtin_amdgcn_s_setprio(0);
            __builtin_amdgcn_sched_barrier(0);
            __builtin_amdgcn_s_barrier();
        }
        // ---------- phase q1: compute ks1 ----------
        {
            half8 af[4], bf[4];
#pragma unroll
            for (int i = 0; i < 4; ++i) af[i] = ldA(rg1, i);
#pragma unroll
            for (int j = 0; j < 4; ++j) bf[j] = ldB(rg1, j);
            if (k + 2 < 18) {
                int kc = (k + 2) * 64;
                stA(rg0, kc); stB(rg0, kc);
                asm volatile("s_waitcnt vmcnt(8) lgkmcnt(0)" ::: "memory");
            } else {
                asm volatile("s_waitcnt vmcnt(0) lgkmcnt(0)" ::: "memory");
            }
            __builtin_amdgcn_s_barrier();
            __builtin_amdgcn_sched_barrier(0);
            __builtin_amdgcn_s_setprio(1);
#pragma unroll
            for (int i = 0; i < 4; ++i)
#pragma unroll
                for (int j = 0; j < 4; ++j)
                    acc[i][j] = __builtin_amdgcn_mfma_f32_16x16x32_f16(af[i], bf[j], acc[i][j], 0, 0, 0);
            __builtin_amdgcn_s_setprio(0);
            __builtin_amdgcn_sched_barrier(0);
            __builtin_amdgcn_s_barrier();
        }
    }

    // C/D layout: col = lane&15, row = (lane>>4)*4 + reg   [m89-verified]
    const int col = n0 + wn_ * 64 + lm;
#pragma unroll
    for (int i = 0; i < 4; ++i) {
        const int row = m0 + wm * 64 + i * 16 + q * 4;
#pragma unroll
        for (int j = 0; j < 4; ++j)
#pragma unroll
            for (int r = 0; r < 4; ++r)
                Cb[(long)(row + r) * LBF + col + j * 16] = acc[i][j][r];
    }
}

// ---------------- NT GEMM, BK=64, double-buffered LDS (R6 winner) — GEMM2 -----
__device__ __forceinline__ void gemm_compute(const _Float16* lA, const _Float16* lB,
                                             floatx4 (&acc)[4][4],
                                             int wr, int wc, int lm, int pcp) {
    half8 af[4], bf[4];
#pragma unroll
    for (int t = 0; t < 4; t++) {
        af[t] = *(const half8*)&lA[(wr * 64 + t * 16 + lm) * 64 + pcp];
        bf[t] = *(const half8*)&lB[(wc * 64 + t * 16 + lm) * 64 + pcp];
    }
#pragma unroll
    for (int i = 0; i < 4; i++)
#pragma unroll
        for (int j = 0; j < 4; j++)
            acc[i][j] = __builtin_amdgcn_mfma_f32_16x16x32_f16(af[i], bf[j], acc[i][j], 0, 0, 0);
#pragma unroll
    for (int t = 0; t < 4; t++) {
        af[t] = *(const half8*)&lA[(wr * 64 + t * 16 + lm) * 64 + (pcp ^ 32)];
        bf[t] = *(const half8*)&lB[(wc * 64 + t * 16 + lm) * 64 + (pcp ^ 32)];
    }
#pragma unroll
    for (int i = 0; i < 4; i++)
#pragma unroll
        for (int j = 0; j < 4; j++)
            acc[i][j] = __builtin_amdgcn_mfma_f32_16x16x32_f16(af[i], bf[j], acc[i][j], 0, 0, 0);
}

__global__ __launch_bounds__(256)
void gemm_nt64(const _Float16* __restrict__ A, const _Float16* __restrict__ B,
               float* __restrict__ C, int M, int N, int ldk, int swapxy,
               const int* __restrict__ Kpos, int Kstat, long sA, long sB, long sC) {
    A += blockIdx.z * sA; B += blockIdx.z * sB; C += blockIdx.z * sC;
    int K;
    if (Kpos) { int kc = dec_kc(Kpos[0]); K = (kc + 63) & ~63; }
    else K = Kstat;
    const int tid = threadIdx.x;
    const int lane = tid & 63, wave = tid >> 6;
    const int wr = wave >> 1, wc = wave & 1;
    const int bm = swapxy ? blockIdx.x : blockIdx.y;
    const int bn = swapxy ? blockIdx.y : blockIdx.x;
    const int m0 = bm * 128, n0 = bn * 128;

    __shared__ _Float16 sm[4][128 * 64];   // [buf*2 + (A=0/B=1)]: 4 x 16 KB

    floatx4 acc[4][4] = {};

    const int lm = lane & 15, q = lane >> 4;
    const int pcp = (q ^ (lm & 7)) * 8;      // substep-0 phys offset (halves)

    const int srow8 = lane >> 3;
    const int gc = ((lane & 7) ^ srow8) * 8;  // global halves offset (XOR swizzle)
    const _Float16* gA[4]; const _Float16* gB[4];
    int dOff[4];
#pragma unroll
    for (int c = 0; c < 4; c++) {
        int r = (wave * 4 + c) * 8 + srow8;
        gA[c] = A + (long)(m0 + r) * ldk + gc;
        gB[c] = B + (long)(n0 + r) * ldk + gc;
        dOff[c] = (wave * 4 + c) * 512;
    }

    if (K > 0) {
#pragma unroll
        for (int c = 0; c < 4; c++) gll16(gA[c], &sm[0][dOff[c]]);
#pragma unroll
        for (int c = 0; c < 4; c++) gll16(gB[c], &sm[1][dOff[c]]);
        __syncthreads();
        int k0 = 0, buf = 0;
        while (true) {
            int kn = k0 + 64;
            if (kn < K) {
                const int nb = (buf ^ 1) * 2;
#pragma unroll
                for (int c = 0; c < 4; c++) gll16(gA[c] + kn, &sm[nb][dOff[c]]);
#pragma unroll
                for (int c = 0; c < 4; c++) gll16(gB[c] + kn, &sm[nb + 1][dOff[c]]);
            }
            gemm_compute(sm[buf * 2], sm[buf * 2 + 1], acc, wr, wc, lm, pcp);
            __syncthreads();
            k0 = kn; buf ^= 1;
            if (k0 >= K) break;
        }
    }

    // C/D layout: col = lane&15, row = (lane>>4)*4 + reg   [m89-verified]
    const int col = n0 + wc * 64 + lm;
    const int rowq = q * 4;
#pragma unroll
    for (int i = 0; i < 4; i++) {
        int row = m0 + wr * 64 + i * 16 + rowq;
#pragma unroll
        for (int j = 0; j < 4; j++)
#pragma unroll
            for (int r = 0; r < 4; r++)
                C[(long)(row + r) * N + col + j * 16] = acc[i][j][r];
    }
}

// ---------------- fuse pass A: FT1[y][x] = sum_d ST[y+d][x+d], float4 ---------
// out[x] = r1[x] + m0*(x>0 ? r0[x-1]:0) + m2*(x<LBF-1 ? r2[x+1]:0)
// 3 aligned float4 loads + 2 scalar edge loads per 4 outputs, float4 store.
__global__ __launch_bounds__(256)
void fuseA(const float* __restrict__ ST, float* __restrict__ FT1) {
    int y = blockIdx.x, bb = blockIdx.y;
    const float* S = ST + (long)bb * LBF * LBF;
    float* F = FT1 + (long)bb * LBF * LBF;
    const float* r0 = S + (long)(y > 0 ? y - 1 : 0) * LBF;
    const float* r1 = S + (long)y * LBF;
    const float* r2 = S + (long)(y < LBF - 1 ? y + 1 : y) * LBF;
    float m0 = (y > 0) ? 1.f : 0.f;
    float m2 = (y < LBF - 1) ? 1.f : 0.f;
    float* o = F + (long)y * LBF;
    int tid = threadIdx.x;
#pragma unroll
    for (int u = 0; u < 3; u++) {
        int qq = tid + u * 256;              // float4 index [0, 576)
        if (qq < LBF / 4) {
            int x0 = qq * 4;
            float4 a = *(const float4*)(r1 + x0);
            float4 b = *(const float4*)(r0 + x0);
            float4 c = *(const float4*)(r2 + x0);
            float lo_m1 = (x0 > 0) ? r0[x0 - 1] : 0.f;
            float hi_p4 = (x0 + 4 < LBF) ? r2[x0 + 4] : 0.f;
            float4 out;
            out.x = a.x + m0 * lo_m1 + m2 * c.y;
            out.y = a.y + m0 * b.x + m2 * c.z;
            out.z = a.z + m0 * b.y + m2 * c.w;
            out.w = a.w + m0 * b.z + m2 * hi_p4;
            *(float4*)(o + x0) = out;
        }
    }
}

// ---------------- fuse pass B + masked softmax + compaction + self-pad --------
// (original R0/R1-proven kernel: permuted coalesced row reads, coalesced writes)
__global__ __launch_bounds__(256)
void fuseB_softmax(const float* __restrict__ FT1, const int* __restrict__ pos,
                   _Float16* __restrict__ attTc_g) {
    int j = blockIdx.x, bb = blockIdx.y;
    int tid = threadIdx.x;
    const float* F = FT1 + (long)bb * LBF * LBF;
    _Float16* orow = attTc_g + ((long)bb * LBF + j) * LDK2;
    int Pj = (j % 48) * 48 + j / 48;
    long roff[3]; bool jok[3];
#pragma unroll
    for (int t = 0; t < 3; t++) {
        int j2 = Pj + t - 1;
        jok[t] = (unsigned)j2 < (unsigned)LBF;
        int jc = jok[t] ? j2 : 0;
        roff[t] = (long)((jc % 48) * 48 + jc / 48) * LBF;
    }
    float v[9]; int ps[9];
    float mx = -1e30f;
#pragma unroll
    for (int u = 0; u < 9; u++) {
        int x = tid + u * 256;
        int sp = pos[x];
        ps[u] = sp;
        float xv = 0.f;
        if (sp >= 0) {
            int a = x / 48, b = x - a * 48;
            int Px = b * 48 + a;
            float acc = 0.f;
#pragma unroll
            for (int t = 0; t < 3; t++) {
                int d2 = t - 1;
                int uu = Px + d2;
                if (jok[t] && (unsigned)uu < (unsigned)LBF) {
                    int ad = a + d2;
                    int c = ((unsigned)ad < 48u) ? (x + 48 * d2)
                          : (ad == 48 ? (b + 1) : (2255 + b));
                    acc += F[roff[t] + c];
                }
            }
            xv = acc * 10.f;
        }
        v[u] = xv;
        mx = fmaxf(mx, xv);
    }
    for (int m = 32; m; m >>= 1) mx = fmaxf(mx, __shfl_xor(mx, m));
    __shared__ float sh[4], sh2[4];
    if ((tid & 63) == 0) sh[tid >> 6] = mx;
    __syncthreads();
    mx = fmaxf(fmaxf(sh[0], sh[1]), fmaxf(sh[2], sh[3]));
    float sum = 0.f;
#pragma unroll
    for (int u = 0; u < 9; u++) { v[u] = __expf(v[u] - mx); sum += v[u]; }
    for (int m = 32; m; m >>= 1) sum += __shfl_xor(sum, m);
    if ((tid & 63) == 0) sh2[tid >> 6] = sum;
    __syncthreads();
    sum = sh2[0] + sh2[1] + sh2[2] + sh2[3];
    float inv = 1.f / sum;
#pragma unroll
    for (int u = 0; u < 9; u++) {
        if (ps[u] >= 0) orow[ps[u]] = (_Float16)(v[u] * inv);
    }
    int kc = dec_kc(pos[2303]);
    int kp = (kc + 63) & ~63;
    if (tid < kp - kc) orow[kc + tid] = (_Float16)0.f;
}

// ---------------- scatter from MT[n][p]: coalesced transposed-conv gather -----
__global__ void scatter_out(const float* __restrict__ MT_, float* __restrict__ out) {
    int yx = blockIdx.x * 256 + threadIdx.x;  // [0, 9216)
    int c = blockIdx.y, b = blockIdx.z;
    int y = yx / 96, x = yx % 96;
    const float* Mb = MT_ + (long)b * 2048 * LBF;
    float s = 0.f;
    for (int uu = (y + 1) & 1; uu < 4; uu += 2) {
        int fi = (y + 1 - uu) >> 1;
        if ((unsigned)fi >= 48u) continue;
        for (int vv = (x + 1) & 1; vv < 4; vv += 2) {
            int fj = (x + 1 - vv) >> 1;
            if ((unsigned)fj >= 48u) continue;
            s += Mb[(long)(c * 16 + uu * 4 + vv) * LBF + fi * 48 + fj];
        }
    }
    out[(((long)b * 128 + c) * 96 + y) * 96 + x] = 0.25f * s;
}

extern "C" void kernel_launch(void* const* d_in, const int* in_sizes, int n_in,
                              void* d_out, int out_size, void* d_ws, size_t ws_size,
                              hipStream_t stream) {
    const float* f    = (const float*)d_in[0];
    const float* bsrc = (const float*)d_in[1];
    const float* mask = (const float*)d_in[2];
    float* out = (float*)d_out;

    char* ws = (char*)d_ws;
    const size_t offR1  = 84934656;
    const size_t offWn  = offR1 + 21233664;
    const size_t offWtc = offR1 + 42467328;
    const size_t offFT1 = offWtc + 37748736;          // 165150720
    const size_t offPos = offFT1 + 2ul * 21233664;    // 207618048
    const size_t NEED   = offPos + 9216;              // 207627264
    if (ws_size < NEED) return;  // visible failure, no OOB writes

    float*    ST    = (float*)(ws + 0);
    float*    MT    = (float*)(ws + 0);
    _Float16* fp    = (_Float16*)(ws + offR1);
    _Float16* wn    = (_Float16*)(ws + offWn);
    _Float16* attTc = (_Float16*)(ws + offR1);
    _Float16* Wtc   = (_Float16*)(ws + offWtc);
    float*    ds    = (float*)(ws + offFT1);
    float*    FT1   = (float*)(ws + offFT1);   // dead ds slot, 2 batches
    int*      pos   = (int*)(ws + offPos);

    stage_scan<<<dim3(9217), 256, 0, stream>>>(f, bsrc, mask, ds, pos);
    prep_fp<<<dim3(9, 2304, 4), 128, 0, stream>>>(ds, fp);
    prep_wn<<<dim3(2304, 4), 128, 0, stream>>>(ds, wn);
    prep_wtc<<<dim3(9, 128, 4), 256, 0, stream>>>(bsrc, pos, Wtc);

    // GEMM1: ST[j,i] = sum_k fp[j,k] * wn[i,k]  (static K=1152)
    gemm1_cv<<<dim3(1296), 256, 0, stream>>>(fp, wn, ST);

    // original proven fuse split: streaming fuseA (now float4) + fuseB softmax
    for (int g = 0; g < 2; g++) {
        fuseA<<<dim3(LBF, 2), 256, 0, stream>>>(ST + (long)g * 2 * LBF * LBF, FT1);
        fuseB_softmax<<<dim3(LBF, 2), 256, 0, stream>>>(FT1, pos,
            attTc + (long)g * 2 * LBF * LDK2);
    }

    // GEMM2 transposed output, R4 block-order: x sweeps Wtc (A), y pins attTc (B)
    gemm_nt64<<<dim3(16, 18, 4), 256, 0, stream>>>(Wtc, attTc, MT, 2048, 2304, LDK2, 1,
        pos + 2303, 0, (long)2048 * LDK2, (long)2304 * LDK2, (long)2048 * 2304);

    scatter_out<<<dim3(36, 128, 4), 256, 0, stream>>>(MT, out);
}

// Round 9
// 439.922 us; speedup vs baseline: 1.1958x; 1.0501x over previous
//
#include <hip/hip_runtime.h>

typedef _Float16 half8 __attribute__((ext_vector_type(8)));
typedef float floatx4 __attribute__((ext_vector_type(4)));

#define LBF 2304   // Lb == Lf
#define K1  1152
#define LDK2 2304  // worst-case compacted stride (Kc can be up to 2304)

__device__ __forceinline__ void gll16(const _Float16* g, _Float16* l) {
    __builtin_amdgcn_global_load_lds((const __attribute__((address_space(1))) void*)g,
                                     (__attribute__((address_space(3))) void*)l, 16, 0, 0);
}

// decode Kc from signed pos'[2303] (excl-scan encoding: valid->e, masked->-e-1)
__device__ __forceinline__ int dec_kc(int s) { return (s >= 0) ? s + 1 : -s - 1; }

// ---------------- mask scan (single block): mask -> signed compaction pos' ----
// Replaces stage_scan's scan block; the 9216 ds-staging blocks are deleted
// (prep_fw reads f/bsrc directly — ds was an exact copy of the stride-2 view).
__global__ __launch_bounds__(256)
void mask_scan(const float* __restrict__ mask, int* __restrict__ pos) {
    __shared__ float msk[48 * 48];
    int tid = threadIdx.x;
    for (int i = tid; i < 2304; i += 256) {
        int y = i / 48, x = i % 48;
        msk[i] = mask[(8 * y) * 384 + 8 * x];
    }
    __syncthreads();
    int mmb[9], loc[9]; int s = 0;
#pragma unroll
    for (int t = 0; t < 9; t++) {
        int p = tid * 9 + t;
        int pi = p / 48, pj = p % 48;
        float sm = 0.f;
#pragma unroll
        for (int u = 0; u < 3; u++)
#pragma unroll
            for (int v = 0; v < 3; v++) {
                int y = pi - 1 + u, x = pj - 1 + v;
                if ((unsigned)y < 48u && (unsigned)x < 48u)
                    sm += msk[y * 48 + x];
            }
        int m = (sm == 0.f) ? 1 : 0;
        mmb[t] = m; loc[t] = s; s += m;
    }
    __shared__ int sh[256];
    sh[tid] = s; __syncthreads();
    for (int off = 1; off < 256; off <<= 1) {
        int v = (tid >= off) ? sh[tid - off] : 0;
        __syncthreads();
        sh[tid] += v;
        __syncthreads();
    }
    int excl = sh[tid] - s;
#pragma unroll
    for (int t = 0; t < 9; t++) {
        int e = excl + loc[t];
        pos[tid * 9 + t] = mmb[t] ? e : (-e - 1);
    }
}

// ---------------- prep: fp (z=0) and wn (z=1) rows, direct from f / bsrc ------
// fp[b][p][k] = f[b][c][2y][2x] for k=c*9+(u*3+v), y=pi-1+u, x=pj-1+v (bounded)
// wn row = same from bsrc, normalized by sqrt(sum(w^2)+1152*ESC).
__global__ __launch_bounds__(256)
void prep_fw(const float* __restrict__ f, const float* __restrict__ bsrc,
             _Float16* __restrict__ fp, _Float16* __restrict__ wn) {
    int p = blockIdx.x, b = blockIdx.y;
    int pi = p / 48, pj = p % 48, tid = threadIdx.x;
    if (blockIdx.z == 0) {
        const float* fb = f + (long)b * 128 * 96 * 96;
        _Float16* orow = fp + ((long)b * LBF + p) * K1;
#pragma unroll
        for (int i = 0; i < 5; i++) {
            int k = tid + i * 256;
            if (k < K1) {
                int c = k / 9, r = k - 9 * c, u = r / 3, v = r - 3 * u;
                int y = pi - 1 + u, x = pj - 1 + v;
                float val = 0.f;
                if ((unsigned)y < 48u && (unsigned)x < 48u)
                    val = fb[(c * 96 + 2 * y) * 96 + 2 * x];
                orow[k] = (_Float16)val;
            }
        }
    } else {
        const float* bb = bsrc + (long)b * 128 * 96 * 96;
        _Float16* orow = wn + ((long)b * LBF + p) * K1;
        float w[5]; float ss = 0.f;
#pragma unroll
        for (int i = 0; i < 5; i++) {
            int k = tid + i * 256;
            float val = 0.f;
            if (k < K1) {
                int c = k / 9, r = k - 9 * c, u = r / 3, v = r - 3 * u;
                int y = pi - 1 + u, x = pj - 1 + v;
                if ((unsigned)y < 48u && (unsigned)x < 48u)
                    val = bb[(c * 96 + 2 * y) * 96 + 2 * x];
            }
            w[i] = val; ss += val * val;
        }
        for (int m = 32; m; m >>= 1) ss += __shfl_xor(ss, m);
        __shared__ float sh[4];
        if ((tid & 63) == 0) sh[tid >> 6] = ss;
        __syncthreads();
        float denom = sqrtf(sh[0] + sh[1] + sh[2] + sh[3] + 0.1152f);
        float inv = 1.f / denom;
#pragma unroll
        for (int i = 0; i < 5; i++) {
            int k = tid + i * 256;
            if (k < K1) orow[k] = (_Float16)(w[i] * inv);
        }
    }
}

// ---------------- prep: compacted Wt, line-efficient ---------------------------
__global__ void prep_wtc(const float* __restrict__ bsrc, const int* __restrict__ pos,
                         _Float16* __restrict__ wtc) {
    int p = blockIdx.x * 256 + threadIdx.x;   // [0,2304)
    int c = blockIdx.y;                       // [0,128)
    int b = blockIdx.z;
    int sp = pos[p];
    long base = ((long)b * 2048 + c * 16) * LDK2;
    if (sp < 0) {
        int kc = dec_kc(pos[2303]);
        int kp = (kc + 63) & ~63;
        int mo = p + sp + 1;                  // masked ordinal
        if (mo < kp - kc) {
#pragma unroll
            for (int n = 0; n < 16; n++)
                wtc[base + (long)n * LDK2 + kc + mo] = (_Float16)0.f;
        }
        return;
    }
    int pi = p / 48, pj = p % 48;
    const float* src = bsrc + ((long)b * 128 + c) * 96 * 96;
#pragma unroll
    for (int u = 0; u < 4; u++) {
        int y = 2 * pi - 1 + u;
        bool yok = (unsigned)y < 96u;
#pragma unroll
        for (int v = 0; v < 4; v++) {
            int x = 2 * pj - 1 + v;
            float val = 0.f;
            if (yok && (unsigned)x < 96u) val = src[y * 96 + x];
            wtc[base + (long)(u * 4 + v) * LDK2 + sp] = (_Float16)val;
        }
    }
}

// ======================= GEMM1: 128x128 tile, 4 waves, counted-vmcnt ==========
// 64 KB LDS -> 2 blocks/CU + T4 counted-vmcnt rolling pipeline + T1 XCD swizzle.
// R3 race fix: lgkmcnt(0) drained BEFORE the mid barrier (see R3 notes).
#define G1_REG 4096   // 128 * 32 halves (8 KB) per region

__global__ __launch_bounds__(256)
void gemm1_cv(const _Float16* __restrict__ A, const _Float16* __restrict__ B,
              float* __restrict__ C) {
    __shared__ _Float16 SA[4 * G1_REG];
    __shared__ _Float16 SB[4 * G1_REG];

    // 1296 blocks = 4 batch * 18 * 18; bijective XCD swizzle (1296 % 8 == 0)
    int bid = blockIdx.x;
    int wg = (bid & 7) * 162 + (bid >> 3);
    int z = wg / 324; int t = wg - z * 324;
    const int m0 = (t / 18) * 128, n0 = (t % 18) * 128;

    const _Float16* gA = A + (long)z * LBF * K1 + (long)m0 * K1;
    const _Float16* gB = B + (long)z * LBF * K1 + (long)n0 * K1;
    float* Cb = C + (long)z * LBF * LBF;

    const int tid = threadIdx.x;
    const int wave = tid >> 6, lane = tid & 63;
    const int lm = lane & 15, q = lane >> 4;
    const int wm = wave >> 1, wn_ = wave & 1;
    const int soff = (q ^ ((lm >> 1) & 3)) * 8;
    const int srow = lane >> 2;                               // row in 16-row chunk
    const int scol = ((lane & 3) ^ ((lane >> 3) & 3)) * 8;    // swizzled k-halves

    floatx4 acc[4][4] = {};

    auto stA = [&](int reg, int kcol) {  // 8 KB region: 2 glls/thread
        _Float16* dst = SA + reg * G1_REG + wave * 1024;
        gll16(gA + (long)(wave * 32 + srow) * K1 + kcol + scol, dst);
        gll16(gA + (long)(wave * 32 + 16 + srow) * K1 + kcol + scol, dst + 512);
    };
    auto stB = [&](int reg, int kcol) {
        _Float16* dst = SB + reg * G1_REG + wave * 1024;
        gll16(gB + (long)(wave * 32 + srow) * K1 + kcol + scol, dst);
        gll16(gB + (long)(wave * 32 + 16 + srow) * K1 + kcol + scol, dst + 512);
    };
    auto ldA = [&](int reg, int i) -> half8 {
        return *(const half8*)&SA[reg * G1_REG + (wm * 64 + i * 16 + lm) * 32 + soff];
    };
    auto ldB = [&](int reg, int j) -> half8 {
        return *(const half8*)&SB[reg * G1_REG + (wn_ * 64 + j * 16 + lm) * 32 + soff];
    };

    // prologue: [0][0]<-t0ks0, [0][1]<-t0ks1, [1][0]<-t1ks0  (12 glls/thread)
    stA(0, 0);  stB(0, 0);
    stA(1, 32); stB(1, 32);
    stA(2, 64); stB(2, 64);
    asm volatile("s_waitcnt vmcnt(8)" ::: "memory");  // oldest batch (t0ks0) landed
    __builtin_amdgcn_s_barrier();

    for (int k = 0; k < 18; ++k) {
        const int b = k & 1;
        const int rg0 = b * 2, rg1 = rg0 + 1, og1 = (b ^ 1) * 2 + 1;
        // ---------- phase q0: compute ks0 ----------
        {
            half8 af[4], bf[4];
#pragma unroll
            for (int i = 0; i < 4; ++i) af[i] = ldA(rg0, i);
#pragma unroll
            for (int j = 0; j < 4; ++j) bf[j] = ldB(rg0, j);
            if (k + 1 < 18) {
                int kc = (k + 1) * 64 + 32;
                stA(og1, kc); stB(og1, kc);
                asm volatile("s_waitcnt vmcnt(8) lgkmcnt(0)" ::: "memory");
            } else {
                asm volatile("s_waitcnt vmcnt(0) lgkmcnt(0)" ::: "memory");
            }
            __builtin_amdgcn_s_barrier();
            __builtin_amdgcn_sched_barrier(0);
            __builtin_amdgcn_s_setprio(1);
#pragma unroll
            for (int i = 0; i < 4; ++i)
#pragma unroll
                for (int j = 0; j < 4; ++j)
                    acc[i][j] = __builtin_amdgcn_mfma_f32_16x16x32_f16(af[i], bf[j], acc[i][j], 0, 0, 0);
            __builtin_amdgcn_s_setprio(0);
            __builtin_amdgcn_sched_barrier(0);
            __builtin_amdgcn_s_barrier();
        }
        // ---------- phase q1: compute ks1 ----------
        {
            half8 af[4], bf[4];
#pragma unroll
            for (int i = 0; i < 4; ++i) af[i] = ldA(rg1, i);
#pragma unroll
            for (int j = 0; j < 4; ++j) bf[j] = ldB(rg1, j);
            if (k + 2 < 18) {
                int kc = (k + 2) * 64;
                stA(rg0, kc); stB(rg0, kc);
                asm volatile("s_waitcnt vmcnt(8) lgkmcnt(0)" ::: "memory");
            } else {
                asm volatile("s_waitcnt vmcnt(0) lgkmcnt(0)" ::: "memory");
            }
            __builtin_amdgcn_s_barrier();
            __builtin_amdgcn_sched_barrier(0);
            __builtin_amdgcn_s_setprio(1);
#pragma unroll
            for (int i = 0; i < 4; ++i)
#pragma unroll
                for (int j = 0; j < 4; ++j)
                    acc[i][j] = __builtin_amdgcn_mfma_f32_16x16x32_f16(af[i], bf[j], acc[i][j], 0, 0, 0);
            __builtin_amdgcn_s_setprio(0);
            __builtin_amdgcn_sched_barrier(0);
            __builtin_amdgcn_s_barrier();
        }
    }

    // C/D layout: col = lane&15, row = (lane>>4)*4 + reg   [m89-verified]
    const int col = n0 + wn_ * 64 + lm;
#pragma unroll
    for (int i = 0; i < 4; ++i) {
        const int row = m0 + wm * 64 + i * 16 + q * 4;
#pragma unroll
        for (int j = 0; j < 4; ++j)
#pragma unroll
            for (int r = 0; r < 4; ++r)
                Cb[(long)(row + r) * LBF + col + j * 16] = acc[i][j][r];
    }
}

// ---------------- NT GEMM, BK=64, double-buffered LDS (R6 winner) — GEMM2 -----
__device__ __forceinline__ void gemm_compute(const _Float16* lA, const _Float16* lB,
                                             floatx4 (&acc)[4][4],
                                             int wr, int wc, int lm, int pcp) {
    half8 af[4], bf[4];
#pragma unroll
    for (int t = 0; t < 4; t++) {
        af[t] = *(const half8*)&lA[(wr * 64 + t * 16 + lm) * 64 + pcp];
        bf[t] = *(const half8*)&lB[(wc * 64 + t * 16 + lm) * 64 + pcp];
    }
#pragma unroll
    for (int i = 0; i < 4; i++)
#pragma unroll
        for (int j = 0; j < 4; j++)
            acc[i][j] = __builtin_amdgcn_mfma_f32_16x16x32_f16(af[i], bf[j], acc[i][j], 0, 0, 0);
#pragma unroll
    for (int t = 0; t < 4; t++) {
        af[t] = *(const half8*)&lA[(wr * 64 + t * 16 + lm) * 64 + (pcp ^ 32)];
        bf[t] = *(const half8*)&lB[(wc * 64 + t * 16 + lm) * 64 + (pcp ^ 32)];
    }
#pragma unroll
    for (int i = 0; i < 4; i++)
#pragma unroll
        for (int j = 0; j < 4; j++)
            acc[i][j] = __builtin_amdgcn_mfma_f32_16x16x32_f16(af[i], bf[j], acc[i][j], 0, 0, 0);
}

__global__ __launch_bounds__(256)
void gemm_nt64(const _Float16* __restrict__ A, const _Float16* __restrict__ B,
               float* __restrict__ C, int M, int N, int ldk, int swapxy,
               const int* __restrict__ Kpos, int Kstat, long sA, long sB, long sC) {
    A += blockIdx.z * sA; B += blockIdx.z * sB; C += blockIdx.z * sC;
    int K;
    if (Kpos) { int kc = dec_kc(Kpos[0]); K = (kc + 63) & ~63; }
    else K = Kstat;
    const int tid = threadIdx.x;
    const int lane = tid & 63, wave = tid >> 6;
    const int wr = wave >> 1, wc = wave & 1;
    const int bm = swapxy ? blockIdx.x : blockIdx.y;
    const int bn = swapxy ? blockIdx.y : blockIdx.x;
    const int m0 = bm * 128, n0 = bn * 128;

    __shared__ _Float16 sm[4][128 * 64];   // [buf*2 + (A=0/B=1)]: 4 x 16 KB

    floatx4 acc[4][4] = {};

    const int lm = lane & 15, q = lane >> 4;
    const int pcp = (q ^ (lm & 7)) * 8;      // substep-0 phys offset (halves)

    const int srow8 = lane >> 3;
    const int gc = ((lane & 7) ^ srow8) * 8;  // global halves offset (XOR swizzle)
    const _Float16* gA[4]; const _Float16* gB[4];
    int dOff[4];
#pragma unroll
    for (int c = 0; c < 4; c++) {
        int r = (wave * 4 + c) * 8 + srow8;
        gA[c] = A + (long)(m0 + r) * ldk + gc;
        gB[c] = B + (long)(n0 + r) * ldk + gc;
        dOff[c] = (wave * 4 + c) * 512;
    }

    if (K > 0) {
#pragma unroll
        for (int c = 0; c < 4; c++) gll16(gA[c], &sm[0][dOff[c]]);
#pragma unroll
        for (int c = 0; c < 4; c++) gll16(gB[c], &sm[1][dOff[c]]);
        __syncthreads();
        int k0 = 0, buf = 0;
        while (true) {
            int kn = k0 + 64;
            if (kn < K) {
                const int nb = (buf ^ 1) * 2;
#pragma unroll
                for (int c = 0; c < 4; c++) gll16(gA[c] + kn, &sm[nb][dOff[c]]);
#pragma unroll
                for (int c = 0; c < 4; c++) gll16(gB[c] + kn, &sm[nb + 1][dOff[c]]);
            }
            gemm_compute(sm[buf * 2], sm[buf * 2 + 1], acc, wr, wc, lm, pcp);
            __syncthreads();
            k0 = kn; buf ^= 1;
            if (k0 >= K) break;
        }
    }

    // C/D layout: col = lane&15, row = (lane>>4)*4 + reg   [m89-verified]
    const int col = n0 + wc * 64 + lm;
    const int rowq = q * 4;
#pragma unroll
    for (int i = 0; i < 4; i++) {
        int row = m0 + wr * 64 + i * 16 + rowq;
#pragma unroll
        for (int j = 0; j < 4; j++)
#pragma unroll
            for (int r = 0; r < 4; r++)
                C[(long)(row + r) * N + col + j * 16] = acc[i][j][r];
    }
}

// ---------------- fuse pass A: FT1[y][x] = sum_d ST[y+d][x+d], float4 ---------
__global__ __launch_bounds__(256)
void fuseA(const float* __restrict__ ST, float* __restrict__ FT1) {
    int y = blockIdx.x, bb = blockIdx.y;
    const float* S = ST + (long)bb * LBF * LBF;
    float* F = FT1 + (long)bb * LBF * LBF;
    const float* r0 = S + (long)(y > 0 ? y - 1 : 0) * LBF;
    const float* r1 = S + (long)y * LBF;
    const float* r2 = S + (long)(y < LBF - 1 ? y + 1 : y) * LBF;
    float m0 = (y > 0) ? 1.f : 0.f;
    float m2 = (y < LBF - 1) ? 1.f : 0.f;
    float* o = F + (long)y * LBF;
    int tid = threadIdx.x;
#pragma unroll
    for (int u = 0; u < 3; u++) {
        int qq = tid + u * 256;              // float4 index [0, 576)
        if (qq < LBF / 4) {
            int x0 = qq * 4;
            float4 a = *(const float4*)(r1 + x0);
            float4 b = *(const float4*)(r0 + x0);
            float4 c = *(const float4*)(r2 + x0);
            float lo_m1 = (x0 > 0) ? r0[x0 - 1] : 0.f;
            float hi_p4 = (x0 + 4 < LBF) ? r2[x0 + 4] : 0.f;
            float4 out;
            out.x = a.x + m0 * lo_m1 + m2 * c.y;
            out.y = a.y + m0 * b.x + m2 * c.z;
            out.z = a.z + m0 * b.y + m2 * c.w;
            out.w = a.w + m0 * b.z + m2 * hi_p4;
            *(float4*)(o + x0) = out;
        }
    }
}

// ---------------- fuse pass B + masked softmax + compaction + self-pad --------
__global__ __launch_bounds__(256)
void fuseB_softmax(const float* __restrict__ FT1, const int* __restrict__ pos,
                   _Float16* __restrict__ attTc_g) {
    int j = blockIdx.x, bb = blockIdx.y;
    int tid = threadIdx.x;
    const float* F = FT1 + (long)bb * LBF * LBF;
    _Float16* orow = attTc_g + ((long)bb * LBF + j) * LDK2;
    int Pj = (j % 48) * 48 + j / 48;
    long roff[3]; bool jok[3];
#pragma unroll
    for (int t = 0; t < 3; t++) {
        int j2 = Pj + t - 1;
        jok[t] = (unsigned)j2 < (unsigned)LBF;
        int jc = jok[t] ? j2 : 0;
        roff[t] = (long)((jc % 48) * 48 + jc / 48) * LBF;
    }
    float v[9]; int ps[9];
    float mx = -1e30f;
#pragma unroll
    for (int u = 0; u < 9; u++) {
        int x = tid + u * 256;
        int sp = pos[x];
        ps[u] = sp;
        float xv = 0.f;
        if (sp >= 0) {
            int a = x / 48, b = x - a * 48;
            int Px = b * 48 + a;
            float acc = 0.f;
#pragma unroll
            for (int t = 0; t < 3; t++) {
                int d2 = t - 1;
                int uu = Px + d2;
                if (jok[t] && (unsigned)uu < (unsigned)LBF) {
                    int ad = a + d2;
                    int c = ((unsigned)ad < 48u) ? (x + 48 * d2)
                          : (ad == 48 ? (b + 1) : (2255 + b));
                    acc += F[roff[t] + c];
                }
            }
            xv = acc * 10.f;
        }
        v[u] = xv;
        mx = fmaxf(mx, xv);
    }
    for (int m = 32; m; m >>= 1) mx = fmaxf(mx, __shfl_xor(mx, m));
    __shared__ float sh[4], sh2[4];
    if ((tid & 63) == 0) sh[tid >> 6] = mx;
    __syncthreads();
    mx = fmaxf(fmaxf(sh[0], sh[1]), fmaxf(sh[2], sh[3]));
    float sum = 0.f;
#pragma unroll
    for (int u = 0; u < 9; u++) { v[u] = __expf(v[u] - mx); sum += v[u]; }
    for (int m = 32; m; m >>= 1) sum += __shfl_xor(sum, m);
    if ((tid & 63) == 0) sh2[tid >> 6] = sum;
    __syncthreads();
    sum = sh2[0] + sh2[1] + sh2[2] + sh2[3];
    float inv = 1.f / sum;
#pragma unroll
    for (int u = 0; u < 9; u++) {
        if (ps[u] >= 0) orow[ps[u]] = (_Float16)(v[u] * inv);
    }
    int kc = dec_kc(pos[2303]);
    int kp = (kc + 63) & ~63;
    if (tid < kp - kc) orow[kc + tid] = (_Float16)0.f;
}

// ---------------- scatter from MT[n][p]: coalesced transposed-conv gather -----
__global__ void scatter_out(const float* __restrict__ MT_, float* __restrict__ out) {
    int yx = blockIdx.x * 256 + threadIdx.x;  // [0, 9216)
    int c = blockIdx.y, b = blockIdx.z;
    int y = yx / 96, x = yx % 96;
    const float* Mb = MT_ + (long)b * 2048 * LBF;
    float s = 0.f;
    for (int uu = (y + 1) & 1; uu < 4; uu += 2) {
        int fi = (y + 1 - uu) >> 1;
        if ((unsigned)fi >= 48u) continue;
        for (int vv = (x + 1) & 1; vv < 4; vv += 2) {
            int fj = (x + 1 - vv) >> 1;
            if ((unsigned)fj >= 48u) continue;
            s += Mb[(long)(c * 16 + uu * 4 + vv) * LBF + fi * 48 + fj];
        }
    }
    out[(((long)b * 128 + c) * 96 + y) * 96 + x] = 0.25f * s;
}

extern "C" void kernel_launch(void* const* d_in, const int* in_sizes, int n_in,
                              void* d_out, int out_size, void* d_ws, size_t ws_size,
                              hipStream_t stream) {
    const float* f    = (const float*)d_in[0];
    const float* bsrc = (const float*)d_in[1];
    const float* mask = (const float*)d_in[2];
    float* out = (float*)d_out;

    char* ws = (char*)d_ws;
    const size_t offR1  = 84934656;
    const size_t offWn  = offR1 + 21233664;
    const size_t offWtc = offR1 + 42467328;
    const size_t offFT1 = offWtc + 37748736;          // 165150720
    const size_t offPos = offFT1 + 2ul * 21233664;    // 207618048
    const size_t NEED   = offPos + 9216;              // 207627264
    if (ws_size < NEED) return;  // visible failure, no OOB writes

    float*    ST    = (float*)(ws + 0);
    float*    MT    = (float*)(ws + 0);
    _Float16* fp    = (_Float16*)(ws + offR1);
    _Float16* wn    = (_Float16*)(ws + offWn);
    _Float16* attTc = (_Float16*)(ws + offR1);
    _Float16* Wtc   = (_Float16*)(ws + offWtc);
    float*    FT1   = (float*)(ws + offFT1);   // 2-batch FT1 slot
    int*      pos   = (int*)(ws + offPos);

    mask_scan<<<dim3(1), 256, 0, stream>>>(mask, pos);
    prep_fw<<<dim3(2304, 4, 2), 256, 0, stream>>>(f, bsrc, fp, wn);
    prep_wtc<<<dim3(9, 128, 4), 256, 0, stream>>>(bsrc, pos, Wtc);

    // GEMM1: ST[j,i] = sum_k fp[j,k] * wn[i,k]  (static K=1152)
    gemm1_cv<<<dim3(1296), 256, 0, stream>>>(fp, wn, ST);

    // proven fuse split: streaming fuseA (float4) + fuseB softmax
    for (int g = 0; g < 2; g++) {
        fuseA<<<dim3(LBF, 2), 256, 0, stream>>>(ST + (long)g * 2 * LBF * LBF, FT1);
        fuseB_softmax<<<dim3(LBF, 2), 256, 0, stream>>>(FT1, pos,
            attTc + (long)g * 2 * LBF * LDK2);
    }

    // GEMM2 transposed output, R4 block-order: x sweeps Wtc (A), y pins attTc (B)
    gemm_nt64<<<dim3(16, 18, 4), 256, 0, stream>>>(Wtc, attTc, MT, 2048, 2304, LDK2, 1,
        pos + 2303, 0, (long)2048 * LDK2, (long)2304 * LDK2, (long)2048 * 2304);

    scatter_out<<<dim3(36, 128, 4), 256, 0, stream>>>(MT, out);
}